// Round 7
// baseline (1279.630 us; speedup 1.0000x reference)
//
#include <hip/hip_runtime.h>

// RSNEncoder R7: single-phase-per-K-tile GEMMs with whole-tile fragment
// preload: {vmcnt, bar, 20x ds_read (all frags), G-issues, 48 MFMA, bar}.
// Progressive lgkmcnt overlaps LDS reads under the MFMA cluster (R6 showed
// zero overlap: 117us ~= serial model; full overlap ~= 51us).
// A 3-buf + B 2-buf, issue order B(t+1),A(t+2) -> steady vmcnt(4).

#define BDIM 32768
#define DDIM 512
#define BD (BDIM * DDIM)

typedef short bf16x8 __attribute__((ext_vector_type(8)));
typedef float f32x4 __attribute__((ext_vector_type(4)));
typedef unsigned short u16x8 __attribute__((ext_vector_type(8)));

#define AS1 __attribute__((address_space(1)))
#define AS3 __attribute__((address_space(3)))

__device__ __forceinline__ unsigned short f2bf(float f) {
  union { float f; unsigned u; } v; v.f = f;
  return (unsigned short)((v.u + 0x7fffu + ((v.u >> 16) & 1u)) >> 16);  // RNE
}
__device__ __forceinline__ float bf2f(unsigned short b) {
  union { unsigned u; float f; } v; v.u = (unsigned)b << 16; return v.f;
}
__device__ __forceinline__ float sigmf(float x) { return 1.0f / (1.0f + __expf(-x)); }
__device__ __forceinline__ float tanhf_(float x) { return 1.0f - 2.0f / (__expf(2.0f * x) + 1.0f); }
__device__ __forceinline__ void bar() { asm volatile("s_barrier" ::: "memory"); }
#define VMCNT(n) asm volatile("s_waitcnt vmcnt(" #n ")" ::: "memory")

// ---- fp32 -> bf16 (all of x) ----
__global__ void cvt_bf16_all(const float* __restrict__ in, unsigned short* __restrict__ out) {
  const size_t stride = (size_t)gridDim.x * 256;
  for (size_t i = (size_t)blockIdx.x * 256 + threadIdx.x; i < (size_t)BD; i += stride) {
    const size_t o = i * 8;
    const float4 a = *(const float4*)(in + o);
    const float4 b = *(const float4*)(in + o + 4);
    u16x8 v;
    v[0] = f2bf(a.x); v[1] = f2bf(a.y); v[2] = f2bf(a.z); v[3] = f2bf(a.w);
    v[4] = f2bf(b.x); v[5] = f2bf(b.y); v[6] = f2bf(b.z); v[7] = f2bf(b.w);
    *(u16x8*)(out + o) = v;
  }
}

// ---- weight prep: Wg[1536][1024] = [Wih | Whh]; Wm[512][1024] = [w1 | w2] ----
__global__ void prep_w(const float* __restrict__ wih, const float* __restrict__ whh,
                       const float* __restrict__ w1, const float* __restrict__ w2,
                       unsigned short* __restrict__ Wg, unsigned short* __restrict__ Wm) {
  int i = blockIdx.x * 256 + threadIdx.x;
  if (i < 1536 * 1024) {
    const int j = i >> 10, k = i & 1023;
    Wg[i] = f2bf((k < 512) ? wih[j * 512 + k] : whh[j * 512 + (k - 512)]);
  } else {
    i -= 1536 * 1024;
    const int j = i >> 10, k = i & 1023;
    Wm[i] = f2bf((k < 512) ? w1[j * 512 + k] : w2[j * 512 + (k - 512)]);
  }
}

// ================= gates kernel =================
// Block 256 rows x 64 d-cols (192 gate-cols), 8 waves 4m x 2n, wave 64x96.
// LDS: A 3 bufs x 32K @0/32K/64K; B 2 bufs x 24K @96K/120K (144 KB).
// Per K-tile: vmcnt(4); bar; read av[4][2]+bv[6][2]; issue B(t+1),A(t+2);
// 48 MFMA; bar.  acc[fm][ai]: ai 0,1=r  2,3=z  4,5=i_n  6,7=h_n.
__global__ __launch_bounds__(512, 2) void gru_gates(
    const unsigned short* __restrict__ X, const unsigned short* __restrict__ H,
    const unsigned short* __restrict__ Wg, const float* __restrict__ bih,
    const float* __restrict__ bhh, unsigned short* __restrict__ outB) {
  __shared__ char smem[147456];
  const int t = threadIdx.x;
  const int lane = t & 63, wid = t >> 6;
  const int wm = wid >> 1, wn = wid & 1;
  const int xcd = blockIdx.x & 7, ixc = blockIdx.x >> 3;
  const int bm = xcd * 16 + (ixc >> 3);  // 128 m-blocks
  const int bn = ixc & 7;                // 8 d-blocks

  f32x4 acc[4][8];
  const f32x4 z4 = {0.f, 0.f, 0.f, 0.f};
#pragma unroll
  for (int a = 0; a < 4; ++a)
#pragma unroll
    for (int b = 0; b < 8; ++b) acc[a][b] = z4;

  const int trow = t >> 3;
  const int tswz = ((t & 7) * 16) ^ ((trow & 7) << 4);
  int asrc[4], bsrc[3];
#pragma unroll
  for (int i = 0; i < 4; ++i) asrc[i] = (bm * 256 + i * 64 + trow) * 1024 + tswz;
#pragma unroll
  for (int g = 0; g < 3; ++g) bsrc[g] = (g * 512 + bn * 64 + trow) * 2048 + tswz;

  const char* Xc = (const char*)X;
  const char* Hc = (const char*)H;
  const char* Wc = (const char*)Wg;

  auto issA = [&](int tt, int i) {  // -> A buf tt%3 (tt static: loop unrolled)
    const char* base = ((tt < 8) ? Xc : Hc) + (tt & 7) * 128 + asrc[i];
    __builtin_amdgcn_global_load_lds(
        (const AS1 void*)base,
        (AS3 void*)(smem + (tt % 3) * 32768 + i * 8192 + t * 16), 16, 0, 0);
  };
  auto issB = [&](int tt, int g) {  // -> B buf tt&1
    const char* base = Wc + tt * 128 + bsrc[g];
    __builtin_amdgcn_global_load_lds(
        (const AS1 void*)base,
        (AS3 void*)(smem + 98304 + (tt & 1) * 24576 + g * 8192 + t * 16), 16, 0, 0);
  };

  // prologue: B(0), A(0), A(1)  [FIFO; vmcnt(4)@t0 certifies B0+A0, A1 in flight]
  issB(0, 0); issB(0, 1); issB(0, 2);
  issA(0, 0); issA(0, 1); issA(0, 2); issA(0, 3);
  issA(1, 0); issA(1, 1); issA(1, 2); issA(1, 3);

#pragma unroll
  for (int kt = 0; kt < 16; ++kt) {
    if (kt < 15) { VMCNT(4); } else { VMCNT(0); }
    bar();
    const char* pa = smem + (kt % 3) * 32768;
    const char* pb = smem + 98304 + (kt & 1) * 24576;
    // whole-tile fragment preload (read order matches MFMA consumption)
    bf16x8 av[4][2], bv[6][2];
#pragma unroll
    for (int ks = 0; ks < 2; ++ks) {
      const int ksb = ks * 64 + (lane >> 4) * 16;
#pragma unroll
      for (int fm = 0; fm < 4; ++fm) {
        const int r = wm * 64 + fm * 16 + (lane & 15);
        av[fm][ks] = *(const bf16x8*)(pa + r * 128 + (ksb ^ ((r & 7) << 4)));
      }
#pragma unroll
      for (int fn = 0; fn < 6; ++fn) {
        const int c = (fn >> 1) * 64 + (fn & 1) * 32 + wn * 16 + (lane & 15);
        bv[fn][ks] = *(const bf16x8*)(pb + c * 128 + (ksb ^ ((c & 7) << 4)));
      }
    }
    // prefetch issues (FIFO: B(kt+1) then A(kt+2))
    if (kt + 1 < 16) { issB(kt + 1, 0); issB(kt + 1, 1); issB(kt + 1, 2); }
    if (kt + 2 < 16) { issA(kt + 2, 0); issA(kt + 2, 1); issA(kt + 2, 2); issA(kt + 2, 3); }
    __builtin_amdgcn_s_setprio(1);
#pragma unroll
    for (int ks = 0; ks < 2; ++ks)
#pragma unroll
      for (int fn = 0; fn < 6; ++fn) {
        const int ai = (fn < 4 || kt < 8) ? fn : fn + 2;  // n-frags: i_n vs h_n
#pragma unroll
        for (int fm = 0; fm < 4; ++fm)
          acc[fm][ai] = __builtin_amdgcn_mfma_f32_16x16x32_bf16(av[fm][ks], bv[fn][ks],
                                                               acc[fm][ai], 0, 0, 0);
      }
    __builtin_amdgcn_s_setprio(0);
    bar();
  }

  // epilogue: gate math (C/D map col=lane&15, row=(lane>>4)*4+j)
  const int erow = (lane >> 4) * 4, ecol = lane & 15;
#pragma unroll
  for (int e = 0; e < 2; ++e) {
    const int d = bn * 64 + e * 32 + wn * 16 + ecol;
    const float br = bih[d] + bhh[d];
    const float bz = bih[512 + d] + bhh[512 + d];
    const float bi = bih[1024 + d];
    const float bh = bhh[1024 + d];
#pragma unroll
    for (int fm = 0; fm < 4; ++fm)
#pragma unroll
      for (int j = 0; j < 4; ++j) {
        const int row = bm * 256 + wm * 64 + fm * 16 + erow + j;
        const size_t off = (size_t)row * 512 + d;
        const float rv = sigmf(acc[fm][0 + e][j] + br);
        const float zv = sigmf(acc[fm][2 + e][j] + bz);
        const float nv = tanhf_(acc[fm][4 + e][j] + bi + rv * (acc[fm][6 + e][j] + bh));
        outB[off] = f2bf((1.0f - zv) * nv + zv * bf2f(H[off]));
      }
  }
}

// ================= mixed kernel: out = [h | x_prev] @ [w1|w2]^T =================
// Block 256 x 128, 8 waves 4m x 2n, wave 64x64. K=1024 (kt<8: h, kt>=8: x_prev).
// LDS: A 3x32K @0/32K/64K; B 2x16K @96K/112K (128 KB). Same schedule as gates.
template <int WF>
__global__ __launch_bounds__(512, 2) void mixed_gemm(
    const unsigned short* __restrict__ Ka, const unsigned short* __restrict__ Kb,
    const unsigned short* __restrict__ Wm,
    unsigned short* __restrict__ outB, float* __restrict__ outF) {
  __shared__ char smem[131072];
  const int t = threadIdx.x;
  const int lane = t & 63, wid = t >> 6;
  const int wm = wid >> 1, wn = wid & 1;
  const int xcd = blockIdx.x & 7, ixc = blockIdx.x >> 3;  // grid 512: ixc in [0,64)
  const int bm = xcd * 16 + (ixc >> 2);  // 128 m-blocks
  const int bn = ixc & 3;                // 4 n-blocks of 128

  f32x4 acc[4][4];
  const f32x4 z4 = {0.f, 0.f, 0.f, 0.f};
#pragma unroll
  for (int a = 0; a < 4; ++a)
#pragma unroll
    for (int b = 0; b < 4; ++b) acc[a][b] = z4;

  const int trow = t >> 3;
  const int tswz = ((t & 7) * 16) ^ ((trow & 7) << 4);
  int asrc[4], bsrc[2];
#pragma unroll
  for (int i = 0; i < 4; ++i) asrc[i] = (bm * 256 + i * 64 + trow) * 1024 + tswz;
#pragma unroll
  for (int j = 0; j < 2; ++j) bsrc[j] = (bn * 128 + j * 64 + trow) * 2048 + tswz;

  const char* Kac = (const char*)Ka;
  const char* Kbc = (const char*)Kb;
  const char* Wc = (const char*)Wm;

  auto issA = [&](int tt, int i) {
    const char* base = ((tt < 8) ? Kac : Kbc) + (tt & 7) * 128 + asrc[i];
    __builtin_amdgcn_global_load_lds(
        (const AS1 void*)base,
        (AS3 void*)(smem + (tt % 3) * 32768 + i * 8192 + t * 16), 16, 0, 0);
  };
  auto issB = [&](int tt, int j) {
    const char* base = Wc + tt * 128 + bsrc[j];
    __builtin_amdgcn_global_load_lds(
        (const AS1 void*)base,
        (AS3 void*)(smem + 98304 + (tt & 1) * 16384 + j * 8192 + t * 16), 16, 0, 0);
  };

  issB(0, 0); issB(0, 1);
  issA(0, 0); issA(0, 1); issA(0, 2); issA(0, 3);
  issA(1, 0); issA(1, 1); issA(1, 2); issA(1, 3);

#pragma unroll
  for (int kt = 0; kt < 16; ++kt) {
    if (kt < 15) { VMCNT(4); } else { VMCNT(0); }
    bar();
    const char* pa = smem + (kt % 3) * 32768;
    const char* pb = smem + 98304 + (kt & 1) * 16384;
    bf16x8 av[4][2], bv[4][2];
#pragma unroll
    for (int ks = 0; ks < 2; ++ks) {
      const int ksb = ks * 64 + (lane >> 4) * 16;
#pragma unroll
      for (int fm = 0; fm < 4; ++fm) {
        const int r = wm * 64 + fm * 16 + (lane & 15);
        av[fm][ks] = *(const bf16x8*)(pa + r * 128 + (ksb ^ ((r & 7) << 4)));
      }
#pragma unroll
      for (int fn = 0; fn < 4; ++fn) {
        const int c = wn * 64 + fn * 16 + (lane & 15);
        bv[fn][ks] = *(const bf16x8*)(pb + c * 128 + (ksb ^ ((c & 7) << 4)));
      }
    }
    if (kt + 1 < 16) { issB(kt + 1, 0); issB(kt + 1, 1); }
    if (kt + 2 < 16) { issA(kt + 2, 0); issA(kt + 2, 1); issA(kt + 2, 2); issA(kt + 2, 3); }
    __builtin_amdgcn_s_setprio(1);
#pragma unroll
    for (int ks = 0; ks < 2; ++ks)
#pragma unroll
      for (int fn = 0; fn < 4; ++fn)
#pragma unroll
        for (int fm = 0; fm < 4; ++fm)
          acc[fm][fn] = __builtin_amdgcn_mfma_f32_16x16x32_bf16(av[fm][ks], bv[fn][ks],
                                                               acc[fm][fn], 0, 0, 0);
    __builtin_amdgcn_s_setprio(0);
    bar();
  }

  const int erow = (lane >> 4) * 4, ecol = lane & 15;
#pragma unroll
  for (int fm = 0; fm < 4; ++fm)
#pragma unroll
    for (int fn = 0; fn < 4; ++fn) {
      const int col = bn * 128 + wn * 64 + fn * 16 + ecol;
#pragma unroll
      for (int j = 0; j < 4; ++j) {
        const int row = bm * 256 + wm * 64 + fm * 16 + erow + j;
        const size_t off = (size_t)row * 512 + col;
        const float v = acc[fm][fn][j];
        if constexpr (WF) outF[off] = v;
        else              outB[off] = f2bf(v);
      }
    }
}

extern "C" void kernel_launch(void* const* d_in, const int* in_sizes, int n_in,
                              void* d_out, int out_size, void* d_ws, size_t ws_size,
                              hipStream_t stream) {
  const float* x   = (const float*)d_in[0];
  const float* wih = (const float*)d_in[1];
  const float* whh = (const float*)d_in[2];
  const float* bih = (const float*)d_in[3];
  const float* bhh = (const float*)d_in[4];
  const float* w1  = (const float*)d_in[5];
  const float* w2  = (const float*)d_in[6];

  char* ws = (char*)d_ws;
  const size_t bd2 = (size_t)BD * 2;
  unsigned short* xall  = (unsigned short*)ws;                  // 8 x 32 MB
  unsigned short* hb[2] = {(unsigned short*)(ws + 8 * bd2),
                           (unsigned short*)(ws + 9 * bd2)};    // 32 MB each
  unsigned short* Wg = (unsigned short*)(ws + 10 * bd2);        // 3 MB
  unsigned short* Wm = Wg + 1536 * 1024;                        // 1 MB

  hipMemsetAsync(hb[0], 0, bd2, stream);  // h0 = 0
  cvt_bf16_all<<<2048, 256, 0, stream>>>(x, xall);
  prep_w<<<8192, 256, 0, stream>>>(wih, whh, w1, w2, Wg, Wm);

  int hp = 0;
  for (int i = 0; i < 8; ++i) {
    const unsigned short* xi = xall + (size_t)i * BD;
    gru_gates<<<1024, 512, 0, stream>>>(xi, hb[hp], Wg, bih, bhh, hb[hp ^ 1]);
    hp ^= 1;
    if (i & 1) {
      const unsigned short* xprev = xall + (size_t)(i - 1) * BD;
      if (i == 7)
        mixed_gemm<1><<<512, 512, 0, stream>>>(hb[hp], xprev, Wm, nullptr, (float*)d_out);
      else
        mixed_gemm<0><<<512, 512, 0, stream>>>(hb[hp], xprev, Wm, hb[hp ^ 1], nullptr);
      if (i != 7) hp ^= 1;
    }
  }
}

// Round 8
// 1224.310 us; speedup vs baseline: 1.0452x; 1.0452x over previous
//
#include <hip/hip_runtime.h>

// RSNEncoder R8: gates kernel at m201-exact phase granularity:
// 4 phases/K-tile = (ks, fm-half): {reads(8/2), stage-issues, [vmcnt@ph3],
// s_barrier, lgkmcnt(0), setprio+12 MFMA, s_barrier}. bv persists across the
// fm-half pair. A 3-buf / B 2-buf, steady VMCNT(4)@ph3, VMCNT(0)@kt14.
// Mixed GEMM + launch structure = R6 verbatim (1229us config).

#define BDIM 32768
#define DDIM 512
#define BD (BDIM * DDIM)

typedef short bf16x8 __attribute__((ext_vector_type(8)));
typedef float f32x4 __attribute__((ext_vector_type(4)));
typedef unsigned short u16x8 __attribute__((ext_vector_type(8)));

#define AS1 __attribute__((address_space(1)))
#define AS3 __attribute__((address_space(3)))

__device__ __forceinline__ unsigned short f2bf(float f) {
  union { float f; unsigned u; } v; v.f = f;
  return (unsigned short)((v.u + 0x7fffu + ((v.u >> 16) & 1u)) >> 16);  // RNE
}
__device__ __forceinline__ float bf2f(unsigned short b) {
  union { unsigned u; float f; } v; v.u = (unsigned)b << 16; return v.f;
}
__device__ __forceinline__ float sigmf(float x) { return 1.0f / (1.0f + __expf(-x)); }
__device__ __forceinline__ float tanhf_(float x) { return 1.0f - 2.0f / (__expf(2.0f * x) + 1.0f); }
__device__ __forceinline__ void bar() { asm volatile("s_barrier" ::: "memory"); }
#define LGKM0 asm volatile("s_waitcnt lgkmcnt(0)" ::: "memory")
#define VMCNT(n) asm volatile("s_waitcnt vmcnt(" #n ")" ::: "memory")

// ---- fp32 -> bf16 (all of x) ----
__global__ void cvt_bf16_all(const float* __restrict__ in, unsigned short* __restrict__ out) {
  const size_t stride = (size_t)gridDim.x * 256;
  for (size_t i = (size_t)blockIdx.x * 256 + threadIdx.x; i < (size_t)BD; i += stride) {
    const size_t o = i * 8;
    const float4 a = *(const float4*)(in + o);
    const float4 b = *(const float4*)(in + o + 4);
    u16x8 v;
    v[0] = f2bf(a.x); v[1] = f2bf(a.y); v[2] = f2bf(a.z); v[3] = f2bf(a.w);
    v[4] = f2bf(b.x); v[5] = f2bf(b.y); v[6] = f2bf(b.z); v[7] = f2bf(b.w);
    *(u16x8*)(out + o) = v;
  }
}

// ---- weight prep: Wg[1536][1024] = [Wih | Whh]; Wm[512][1024] = [w1 | w2] ----
__global__ void prep_w(const float* __restrict__ wih, const float* __restrict__ whh,
                       const float* __restrict__ w1, const float* __restrict__ w2,
                       unsigned short* __restrict__ Wg, unsigned short* __restrict__ Wm) {
  int i = blockIdx.x * 256 + threadIdx.x;
  if (i < 1536 * 1024) {
    const int j = i >> 10, k = i & 1023;
    Wg[i] = f2bf((k < 512) ? wih[j * 512 + k] : whh[j * 512 + (k - 512)]);
  } else {
    i -= 1536 * 1024;
    const int j = i >> 10, k = i & 1023;
    Wm[i] = f2bf((k < 512) ? w1[j * 512 + k] : w2[j * 512 + (k - 512)]);
  }
}

// ================= gates kernel =================
// Block 256 rows x 64 d (192 gate-cols), 8 waves 4m x 2n, wave 64x96.
// LDS: A 3 bufs x 32K @0/32K/64K; B 2 bufs x 24K @96K/120K (144 KB).
// acc[fm][ai]: ai 0,1=r  2,3=z  4,5=i_n  6,7=h_n.
__global__ __launch_bounds__(512, 2) void gru_gates(
    const unsigned short* __restrict__ X, const unsigned short* __restrict__ H,
    const unsigned short* __restrict__ Wg, const float* __restrict__ bih,
    const float* __restrict__ bhh, unsigned short* __restrict__ outB) {
  __shared__ char smem[147456];
  const int t = threadIdx.x;
  const int lane = t & 63, wid = t >> 6;
  const int wm = wid >> 1, wn = wid & 1;
  const int xcd = blockIdx.x & 7, ixc = blockIdx.x >> 3;
  const int bm = xcd * 16 + (ixc >> 3);  // 128 m-blocks
  const int bn = ixc & 7;                // 8 d-blocks

  f32x4 acc[4][8];
  const f32x4 z4 = {0.f, 0.f, 0.f, 0.f};
#pragma unroll
  for (int a = 0; a < 4; ++a)
#pragma unroll
    for (int b = 0; b < 8; ++b) acc[a][b] = z4;

  const int trow = t >> 3;
  const int tswz = ((t & 7) * 16) ^ ((trow & 7) << 4);
  int asrc[4], bsrc[3];
#pragma unroll
  for (int i = 0; i < 4; ++i) asrc[i] = (bm * 256 + i * 64 + trow) * 1024 + tswz;
#pragma unroll
  for (int g = 0; g < 3; ++g) bsrc[g] = (g * 512 + bn * 64 + trow) * 2048 + tswz;

  const char* Xc = (const char*)X;
  const char* Hc = (const char*)H;
  const char* Wc = (const char*)Wg;

  auto issA = [&](int tt, int i) {  // -> A buf tt%3 (tt static under unroll)
    const char* base = ((tt < 8) ? Xc : Hc) + (tt & 7) * 128 + asrc[i];
    __builtin_amdgcn_global_load_lds(
        (const AS1 void*)base,
        (AS3 void*)(smem + (tt % 3) * 32768 + i * 8192 + t * 16), 16, 0, 0);
  };
  auto issB = [&](int tt, int g) {  // -> B buf tt&1
    const char* base = Wc + tt * 128 + bsrc[g];
    __builtin_amdgcn_global_load_lds(
        (const AS1 void*)base,
        (AS3 void*)(smem + 98304 + (tt & 1) * 24576 + g * 8192 + t * 16), 16, 0, 0);
  };

  const int arow0 = wm * 64 + (lane & 15);
  const int kcol0 = (lane >> 4) * 16;
  auto rdA = [&](const char* pa, int fm, int ks) -> bf16x8 {
    const int r = arow0 + fm * 16;
    const int c = ks * 64 + kcol0;
    return *(const bf16x8*)(pa + r * 128 + (c ^ ((r & 7) << 4)));
  };
  auto rdB = [&](const char* pb, int fn, int ks) -> bf16x8 {
    const int r = (fn >> 1) * 64 + (fn & 1) * 32 + wn * 16 + (lane & 15);
    const int c = ks * 64 + kcol0;
    return *(const bf16x8*)(pb + r * 128 + (c ^ ((r & 7) << 4)));
  };

// 12 MFMA with fm base FB (literal) consuming av0,av1 + bv[6]; kt literal.
#define MM(FB, KT)                                                                     \
  do {                                                                                 \
    __builtin_amdgcn_s_setprio(1);                                                     \
    _Pragma("unroll") for (int fn = 0; fn < 6; ++fn) {                                 \
      const int ai = (fn < 4 || (KT) < 8) ? fn : fn + 2;                               \
      acc[FB][ai] =                                                                    \
          __builtin_amdgcn_mfma_f32_16x16x32_bf16(av0, bv[fn], acc[FB][ai], 0, 0, 0);  \
      acc[(FB) + 1][ai] = __builtin_amdgcn_mfma_f32_16x16x32_bf16(av1, bv[fn],         \
                                                                 acc[(FB) + 1][ai], 0, 0, 0); \
    }                                                                                  \
    __builtin_amdgcn_s_setprio(0);                                                     \
  } while (0)

  // prologue: B(0) x3, A(0) x4, A(1) x4; certify B0+A0 (A1 stays in flight)
  issB(0, 0); issB(0, 1); issB(0, 2);
  issA(0, 0); issA(0, 1); issA(0, 2); issA(0, 3);
  issA(1, 0); issA(1, 1); issA(1, 2); issA(1, 3);
  VMCNT(4);
  bar();

#pragma unroll
  for (int kt = 0; kt < 16; ++kt) {
    const char* pa = smem + (kt % 3) * 32768;
    const char* pb = smem + 98304 + (kt & 1) * 24576;
    bf16x8 av0, av1, bv[6];
    // ---- ph0: ks0, fm{0,1} ----
    av0 = rdA(pa, 0, 0); av1 = rdA(pa, 1, 0);
#pragma unroll
    for (int fn = 0; fn < 6; ++fn) bv[fn] = rdB(pb, fn, 0);
    if (kt + 1 < 16) { issB(kt + 1, 0); issB(kt + 1, 1); }
    bar(); LGKM0;
    MM(0, kt);
    bar();
    // ---- ph1: ks0, fm{2,3} (bv reused) ----
    av0 = rdA(pa, 2, 0); av1 = rdA(pa, 3, 0);
    if (kt + 1 < 16) issB(kt + 1, 2);
    if (kt + 2 < 16) issA(kt + 2, 0);
    bar(); LGKM0;
    MM(2, kt);
    bar();
    // ---- ph2: ks1, fm{0,1} ----
    av0 = rdA(pa, 0, 1); av1 = rdA(pa, 1, 1);
#pragma unroll
    for (int fn = 0; fn < 6; ++fn) bv[fn] = rdB(pb, fn, 1);
    if (kt + 2 < 16) { issA(kt + 2, 1); issA(kt + 2, 2); }
    bar(); LGKM0;
    MM(0, kt);
    bar();
    // ---- ph3: ks1, fm{2,3}; certify NEXT tile before its reads ----
    av0 = rdA(pa, 2, 1); av1 = rdA(pa, 3, 1);
    if (kt + 2 < 16) issA(kt + 2, 3);
    if (kt < 14) { VMCNT(4); }          // B(t+1) last + A(t+1) arrived
    else if (kt == 14) { VMCNT(0); }    // drain for tile 15
    bar(); LGKM0;
    MM(2, kt);
    bar();
  }
#undef MM

  // epilogue: gate math (C/D map col=lane&15, row=(lane>>4)*4+j)
  const int erow = (lane >> 4) * 4, ecol = lane & 15;
#pragma unroll
  for (int e = 0; e < 2; ++e) {
    const int d = bn * 64 + e * 32 + wn * 16 + ecol;
    const float br = bih[d] + bhh[d];
    const float bz = bih[512 + d] + bhh[512 + d];
    const float bi = bih[1024 + d];
    const float bh = bhh[1024 + d];
#pragma unroll
    for (int fm = 0; fm < 4; ++fm)
#pragma unroll
      for (int j = 0; j < 4; ++j) {
        const int row = bm * 256 + wm * 64 + fm * 16 + erow + j;
        const size_t off = (size_t)row * 512 + d;
        const float rv = sigmf(acc[fm][0 + e][j] + br);
        const float zv = sigmf(acc[fm][2 + e][j] + bz);
        const float nv = tanhf_(acc[fm][4 + e][j] + bi + rv * (acc[fm][6 + e][j] + bh));
        outB[off] = f2bf((1.0f - zv) * nv + zv * bf2f(H[off]));
      }
  }
}

// ================= mixed kernel (R6/R3 verbatim) =================
template <int MH, int NH>
__device__ __forceinline__ void mfmaQ(f32x4 (&acc)[8][4], const bf16x8 (&af)[4][2],
                                      const bf16x8 (&bv)[2][2]) {
  __builtin_amdgcn_s_setprio(1);
#pragma unroll
  for (int fm = 0; fm < 4; ++fm)
#pragma unroll
    for (int fn = 0; fn < 2; ++fn)
#pragma unroll
      for (int ks = 0; ks < 2; ++ks)
        acc[MH * 4 + fm][NH * 2 + fn] = __builtin_amdgcn_mfma_f32_16x16x32_bf16(
            af[fm][ks], bv[fn][ks], acc[MH * 4 + fm][NH * 2 + fn], 0, 0, 0);
  __builtin_amdgcn_s_setprio(0);
}

template <int WF>
__global__ __launch_bounds__(512, 2) void mixed_gemm(
    const unsigned short* __restrict__ Ka, const unsigned short* __restrict__ Kb,
    const unsigned short* __restrict__ Wm,
    unsigned short* __restrict__ outB, float* __restrict__ outF) {
  __shared__ char smem[131072];
  const int t = threadIdx.x;
  const int lane = t & 63, wid = t >> 6;
  const int wm = wid >> 2, wn = wid & 3;
  const int xcd = blockIdx.x & 7, ixc = blockIdx.x >> 3;
  const int bm = xcd * 16 + (ixc >> 1);
  const int bn = ixc & 1;

  f32x4 acc[8][4];
  const f32x4 z4 = {0.f, 0.f, 0.f, 0.f};
#pragma unroll
  for (int a = 0; a < 8; ++a)
#pragma unroll
    for (int b = 0; b < 4; ++b) acc[a][b] = z4;

  const int trow = t >> 3;
  const int tswz = ((t & 7) * 16) ^ ((trow & 7) << 4);
  int asrc[4], bsrc[4];
#pragma unroll
  for (int i = 0; i < 4; ++i) {
    asrc[i] = (bm * 256 + i * 64 + trow) * 1024 + tswz;
    bsrc[i] = (bn * 256 + i * 64 + trow) * 2048 + tswz;
  }
  const char* Kac = (const char*)Ka;
  const char* Kbc = (const char*)Kb;
  const char* Wc = (const char*)Wm;

  auto issA = [&](int kt, int i) {
    const char* base = ((kt < 8) ? Kac : Kbc) + (kt & 7) * 128 + asrc[i];
    __builtin_amdgcn_global_load_lds(
        (const AS1 void*)base,
        (AS3 void*)(smem + (kt & 1) * 65536 + i * 8192 + t * 16), 16, 0, 0);
  };
  auto issB = [&](int kt, int i) {
    const char* base = Wc + kt * 128 + bsrc[i];
    __builtin_amdgcn_global_load_lds(
        (const AS1 void*)base,
        (AS3 void*)(smem + (kt & 1) * 65536 + 32768 + i * 8192 + t * 16), 16, 0, 0);
  };

  bf16x8 af[4][2], bf0[2][2], bf1[2][2];
  auto readAm = [&](const char* pa, int mh) {
#pragma unroll
    for (int fm = 0; fm < 4; ++fm)
#pragma unroll
      for (int ks = 0; ks < 2; ++ks) {
        const int r = mh * 128 + wm * 64 + fm * 16 + (lane & 15);
        const int c = ks * 64 + (lane >> 4) * 16;
        af[fm][ks] = *(const bf16x8*)(pa + r * 128 + (c ^ ((r & 7) << 4)));
      }
  };
  auto readBm = [&](const char* pb, int nh, bf16x8 (&bv)[2][2]) {
#pragma unroll
    for (int fn = 0; fn < 2; ++fn)
#pragma unroll
      for (int ks = 0; ks < 2; ++ks) {
        const int r = nh * 128 + wn * 32 + fn * 16 + (lane & 15);
        const int c = ks * 64 + (lane >> 4) * 16;
        bv[fn][ks] = *(const bf16x8*)(pb + r * 128 + (c ^ ((r & 7) << 4)));
      }
  };

  issA(0, 0); issA(0, 1); issB(0, 0); issB(0, 1);
  issB(0, 2); issB(0, 3); issA(0, 2); issA(0, 3);
  VMCNT(4);
  bar();

  for (int kt = 0; kt < 16; ++kt) {
    const bool last = (kt == 15);
    const char* pa = smem + (kt & 1) * 65536;
    const char* pb = pa + 32768;
    readAm(pa, 0);
    readBm(pb, 0, bf0);
    if (!last) { issA(kt + 1, 0); issA(kt + 1, 1); VMCNT(4); }
    else       { VMCNT(2); }
    bar();
    mfmaQ<0, 0>(acc, af, bf0);
    bar();
    readBm(pb, 1, bf1);
    if (!last) { issB(kt + 1, 0); issB(kt + 1, 1); VMCNT(4); }
    else       { VMCNT(0); }
    bar();
    mfmaQ<0, 1>(acc, af, bf1);
    bar();
    readAm(pa, 1);
    if (!last) { issB(kt + 1, 2); issB(kt + 1, 3); }
    bar();
    mfmaQ<1, 0>(acc, af, bf0);
    bar();
    if (!last) { issA(kt + 1, 2); issA(kt + 1, 3); VMCNT(4); }
    bar();
    mfmaQ<1, 1>(acc, af, bf1);
    bar();
  }

  const int erow = (lane >> 4) * 4, ecol = lane & 15;
#pragma unroll
  for (int mh = 0; mh < 2; ++mh)
#pragma unroll
    for (int fm = 0; fm < 4; ++fm)
#pragma unroll
      for (int nh = 0; nh < 2; ++nh)
#pragma unroll
        for (int fn = 0; fn < 2; ++fn) {
          const int col = bn * 256 + nh * 128 + wn * 32 + fn * 16 + ecol;
#pragma unroll
          for (int j = 0; j < 4; ++j) {
            const int row = bm * 256 + mh * 128 + wm * 64 + fm * 16 + erow + j;
            const size_t off = (size_t)row * 512 + col;
            const float v = acc[mh * 4 + fm][nh * 2 + fn][j];
            if constexpr (WF) outF[off] = v;
            else              outB[off] = f2bf(v);
          }
        }
}

extern "C" void kernel_launch(void* const* d_in, const int* in_sizes, int n_in,
                              void* d_out, int out_size, void* d_ws, size_t ws_size,
                              hipStream_t stream) {
  const float* x   = (const float*)d_in[0];
  const float* wih = (const float*)d_in[1];
  const float* whh = (const float*)d_in[2];
  const float* bih = (const float*)d_in[3];
  const float* bhh = (const float*)d_in[4];
  const float* w1  = (const float*)d_in[5];
  const float* w2  = (const float*)d_in[6];

  char* ws = (char*)d_ws;
  const size_t bd2 = (size_t)BD * 2;
  unsigned short* xall  = (unsigned short*)ws;                  // 8 x 32 MB
  unsigned short* hb[2] = {(unsigned short*)(ws + 8 * bd2),
                           (unsigned short*)(ws + 9 * bd2)};    // 32 MB each
  unsigned short* Wg = (unsigned short*)(ws + 10 * bd2);        // 3 MB
  unsigned short* Wm = Wg + 1536 * 1024;                        // 1 MB

  hipMemsetAsync(hb[0], 0, bd2, stream);  // h0 = 0
  cvt_bf16_all<<<2048, 256, 0, stream>>>(x, xall);
  prep_w<<<8192, 256, 0, stream>>>(wih, whh, w1, w2, Wg, Wm);

  int hp = 0;
  for (int i = 0; i < 8; ++i) {
    const unsigned short* xi = xall + (size_t)i * BD;
    gru_gates<<<1024, 512, 0, stream>>>(xi, hb[hp], Wg, bih, bhh, hb[hp ^ 1]);
    hp ^= 1;
    if (i & 1) {
      const unsigned short* xprev = xall + (size_t)(i - 1) * BD;
      if (i == 7)
        mixed_gemm<1><<<256, 512, 0, stream>>>(hb[hp], xprev, Wm, nullptr, (float*)d_out);
      else
        mixed_gemm<0><<<256, 512, 0, stream>>>(hb[hp], xprev, Wm, hb[hp ^ 1], nullptr);
      if (i != 7) hp ^= 1;
    }
  }
}